// Round 1
// baseline (303.951 us; speedup 1.0000x reference)
//
#include <hip/hip_runtime.h>
#include <math.h>

namespace {
constexpr int Bn = 32, Hn = 1024, Wn = 1024;
constexpr int ROWS = Bn * Hn;                 // 32768 rows total
constexpr int GRID1 = 4096;                   // blocks in pass 1
constexpr int ROWS_PER_BLOCK = ROWS / GRID1;  // 8
constexpr float BWGT = 3.0f;
}

// One row per iteration: 256 threads x 4 px = 1024 = W. up/dn validity is
// block-uniform (no divergence). Edge columns use +/-INF sentinels, matching
// reduce_window's init-value SAME padding.
__global__ __launch_bounds__(256) void bam_bce_rows(
    const float* __restrict__ pred, const float* __restrict__ tgt,
    float* __restrict__ partial)
{
    const int tid = threadIdx.x;
    const int x0 = tid << 2;
    float sum = 0.0f;

    for (int it = 0; it < ROWS_PER_BLOCK; ++it) {
        const int row = blockIdx.x + it * GRID1;
        const int y = row & (Hn - 1);
        const bool up = (y > 0);
        const bool dn = (y < Hn - 1);
        const float* trow = tgt + (size_t)row * Wn;
        const float* prow = pred + (size_t)row * Wn;

        const float4 tc = *reinterpret_cast<const float4*>(trow + x0);
        const float4 p4 = *reinterpret_cast<const float4*>(prow + x0);
        float4 tu = make_float4(0.f, 0.f, 0.f, 0.f), td = tu;
        if (up) tu = *reinterpret_cast<const float4*>(trow - Wn + x0);
        if (dn) td = *reinterpret_cast<const float4*>(trow + Wn + x0);

        const float tcv[4] = {tc.x, tc.y, tc.z, tc.w};
        const float tuv[4] = {tu.x, tu.y, tu.z, tu.w};
        const float tdv[4] = {td.x, td.y, td.z, td.w};
        const float pv[4]  = {p4.x, p4.y, p4.z, p4.w};

        // Column-wise max/min over the 3 rows, for columns x0-1 .. x0+4.
        float cmx[6], cmn[6];
        #pragma unroll
        for (int j = 0; j < 4; ++j) {
            float mx = tcv[j], mn = tcv[j];
            if (up) { mx = fmaxf(mx, tuv[j]); mn = fminf(mn, tuv[j]); }
            if (dn) { mx = fmaxf(mx, tdv[j]); mn = fminf(mn, tdv[j]); }
            cmx[j + 1] = mx; cmn[j + 1] = mn;
        }
        if (tid == 0) {                       // x = -1 (out of image)
            cmx[0] = -INFINITY; cmn[0] = INFINITY;
        } else {
            float a = trow[x0 - 1];
            float mx = a, mn = a;
            if (up) { float v = trow[x0 - 1 - Wn]; mx = fmaxf(mx, v); mn = fminf(mn, v); }
            if (dn) { float v = trow[x0 - 1 + Wn]; mx = fmaxf(mx, v); mn = fminf(mn, v); }
            cmx[0] = mx; cmn[0] = mn;
        }
        if (tid == 255) {                     // x = W (out of image)
            cmx[5] = -INFINITY; cmn[5] = INFINITY;
        } else {
            float a = trow[x0 + 4];
            float mx = a, mn = a;
            if (up) { float v = trow[x0 + 4 - Wn]; mx = fmaxf(mx, v); mn = fminf(mn, v); }
            if (dn) { float v = trow[x0 + 4 + Wn]; mx = fmaxf(mx, v); mn = fminf(mn, v); }
            cmx[5] = mx; cmn[5] = mn;
        }

        #pragma unroll
        for (int i = 0; i < 4; ++i) {
            const float nmx = fmaxf(fmaxf(cmx[i], cmx[i + 1]), cmx[i + 2]);
            const float nmn = fminf(fminf(cmn[i], cmn[i + 1]), cmn[i + 2]);
            const float w = (nmx > nmn) ? BWGT : 1.0f;   // boundary band
            const float t = tcv[i];                      // exactly 0.0 or 1.0
            const float p = pv[i];
            const float x = (t != 0.0f) ? p : (1.0f - p);
            sum += w * (-__logf(x));                     // BCE, one log per px
        }
    }

    // wave(64) shuffle reduce -> 4-wave LDS reduce -> one partial per block
    #pragma unroll
    for (int off = 32; off > 0; off >>= 1) sum += __shfl_down(sum, off);
    __shared__ float smem[4];
    if ((tid & 63) == 0) smem[tid >> 6] = sum;
    __syncthreads();
    if (tid == 0) partial[blockIdx.x] = (smem[0] + smem[1]) + (smem[2] + smem[3]);
}

__global__ __launch_bounds__(256) void bam_bce_reduce(
    const float* __restrict__ partial, float* __restrict__ out)
{
    const int tid = threadIdx.x;
    float s = 0.0f;
    for (int i = tid; i < GRID1; i += 256) s += partial[i];
    #pragma unroll
    for (int off = 32; off > 0; off >>= 1) s += __shfl_down(s, off);
    __shared__ float smem[4];
    if ((tid & 63) == 0) smem[tid >> 6] = s;
    __syncthreads();
    if (tid == 0) {
        const float invN = 1.0f / (float)((long long)Bn * Hn * Wn);  // 1/2^25, exact
        out[0] = ((smem[0] + smem[1]) + (smem[2] + smem[3])) * invN;
    }
}

extern "C" void kernel_launch(void* const* d_in, const int* in_sizes, int n_in,
                              void* d_out, int out_size, void* d_ws, size_t ws_size,
                              hipStream_t stream)
{
    const float* pred = (const float*)d_in[0];
    const float* tgt  = (const float*)d_in[1];
    float* partial = (float*)d_ws;            // 4096 floats = 16 KB, fully
                                              // overwritten each call (poison-safe)
    bam_bce_rows<<<GRID1, 256, 0, stream>>>(pred, tgt, partial);
    bam_bce_reduce<<<1, 256, 0, stream>>>(partial, (float*)d_out);
}

// Round 2
// 287.598 us; speedup vs baseline: 1.0569x; 1.0569x over previous
//
#include <hip/hip_runtime.h>
#include <math.h>

namespace {
constexpr int Bn = 32, Hn = 1024, Wn = 1024;
constexpr int STRIP = 16;                       // rows per block (divides Hn)
constexpr int GRID1 = Bn * Hn / STRIP;          // 2048 blocks
constexpr float BWGT = 3.0f;
}

// Per-row register state: 4 own columns + edge values for wave-boundary lanes.
// Edge regs are only meaningful in lane 0 (eL*) / lane 63 (eR*); for image
// borders (tid 0 / 255) they hold the max-identity 0 / min-identity 1, which
// is exact for binary targets (pad 0 never raises a max, pad 1 never lowers
// a min) — matching reduce_window's -inf/+inf init semantics.
struct Row { float v0, v1, v2, v3, eLmx, eLmn, eRmx, eRmn; };

__device__ inline Row load_trow(const float* __restrict__ trow,
                                int tid, int lane, int x0)
{
    Row r;
    const float4 t = *reinterpret_cast<const float4*>(trow + x0);
    r.v0 = t.x; r.v1 = t.y; r.v2 = t.z; r.v3 = t.w;
    r.eLmx = 0.0f; r.eLmn = 1.0f; r.eRmx = 0.0f; r.eRmn = 1.0f;
    if (lane == 0 && tid != 0)   { float e = trow[x0 - 1]; r.eLmx = e; r.eLmn = e; }
    if (lane == 63 && tid != 255){ float e = trow[x0 + 4]; r.eRmx = e; r.eRmn = e; }
    return r;
}

__global__ __launch_bounds__(256) void bam_bce_rows(
    const float* __restrict__ pred, const float* __restrict__ tgt,
    float* __restrict__ partial)
{
    const int tid  = threadIdx.x;
    const int lane = tid & 63;
    const int x0   = tid << 2;
    const int rowBase = blockIdx.x * STRIP;     // strips never cross images
    const int y0 = rowBase & (Hn - 1);
    const float* tbase = tgt  + (size_t)rowBase * Wn;
    const float* pbase = pred + (size_t)rowBase * Wn;

    Row A = {0,0,0,0, 0.f,1.f,0.f,1.f};
    Row D = A;
    bool hasA = (y0 != 0);
    if (hasA) A = load_trow(tbase - Wn, tid, lane, x0);
    Row B = load_trow(tbase,      tid, lane, x0);
    Row C = load_trow(tbase + Wn, tid, lane, x0);
    bool hasC = true;
    float4 P = *reinterpret_cast<const float4*>(pbase + x0);

    float sum = 0.0f;

    for (int i = 0; i < STRIP; ++i) {
        // ---- prefetch (distance 1): target row y+2, pred row y+1 ----
        const bool hasD = (y0 + i + 2) < Hn;
        if (hasD) D = load_trow(tbase + (size_t)(i + 2) * Wn, tid, lane, x0);
        float4 Pn = P;
        if (i < STRIP - 1)
            Pn = *reinterpret_cast<const float4*>(pbase + (size_t)(i + 1) * Wn + x0);

        // ---- 3-row column max/min (rows y-1..y+1, validity block-uniform) ----
        float cmx0 = B.v0, cmx1 = B.v1, cmx2 = B.v2, cmx3 = B.v3;
        float cmn0 = B.v0, cmn1 = B.v1, cmn2 = B.v2, cmn3 = B.v3;
        float eLmx = B.eLmx, eLmn = B.eLmn, eRmx = B.eRmx, eRmn = B.eRmn;
        if (hasA) {
            cmx0 = fmaxf(cmx0, A.v0); cmn0 = fminf(cmn0, A.v0);
            cmx1 = fmaxf(cmx1, A.v1); cmn1 = fminf(cmn1, A.v1);
            cmx2 = fmaxf(cmx2, A.v2); cmn2 = fminf(cmn2, A.v2);
            cmx3 = fmaxf(cmx3, A.v3); cmn3 = fminf(cmn3, A.v3);
            eLmx = fmaxf(eLmx, A.eLmx); eLmn = fminf(eLmn, A.eLmn);
            eRmx = fmaxf(eRmx, A.eRmx); eRmn = fminf(eRmn, A.eRmn);
        }
        if (hasC) {
            cmx0 = fmaxf(cmx0, C.v0); cmn0 = fminf(cmn0, C.v0);
            cmx1 = fmaxf(cmx1, C.v1); cmn1 = fminf(cmn1, C.v1);
            cmx2 = fmaxf(cmx2, C.v2); cmn2 = fminf(cmn2, C.v2);
            cmx3 = fmaxf(cmx3, C.v3); cmn3 = fminf(cmn3, C.v3);
            eLmx = fmaxf(eLmx, C.eLmx); eLmn = fminf(eLmn, C.eLmn);
            eRmx = fmaxf(eRmx, C.eRmx); eRmn = fminf(eRmn, C.eRmn);
        }

        // ---- neighbor columns via in-wave shuffle; wave edges from e* regs ----
        float Lmx = __shfl_up(cmx3, 1),  Lmn = __shfl_up(cmn3, 1);
        float Rmx = __shfl_down(cmx0, 1), Rmn = __shfl_down(cmn0, 1);
        if (lane == 0)  { Lmx = eLmx; Lmn = eLmn; }
        if (lane == 63) { Rmx = eRmx; Rmn = eRmn; }

        // ---- 3x3 window max/min -> weight -> BCE (t is exactly 0 or 1) ----
        {
            const float wmx = fmaxf(fmaxf(Lmx, cmx0), cmx1);
            const float wmn = fminf(fminf(Lmn, cmn0), cmn1);
            const float w = (wmx > wmn) ? BWGT : 1.0f;
            const float x = (B.v0 != 0.0f) ? P.x : (1.0f - P.x);
            sum = fmaf(w, -__logf(x), sum);
        }
        {
            const float wmx = fmaxf(fmaxf(cmx0, cmx1), cmx2);
            const float wmn = fminf(fminf(cmn0, cmn1), cmn2);
            const float w = (wmx > wmn) ? BWGT : 1.0f;
            const float x = (B.v1 != 0.0f) ? P.y : (1.0f - P.y);
            sum = fmaf(w, -__logf(x), sum);
        }
        {
            const float wmx = fmaxf(fmaxf(cmx1, cmx2), cmx3);
            const float wmn = fminf(fminf(cmn1, cmn2), cmn3);
            const float w = (wmx > wmn) ? BWGT : 1.0f;
            const float x = (B.v2 != 0.0f) ? P.z : (1.0f - P.z);
            sum = fmaf(w, -__logf(x), sum);
        }
        {
            const float wmx = fmaxf(fmaxf(cmx2, cmx3), Rmx);
            const float wmn = fminf(fminf(cmn2, cmn3), Rmn);
            const float w = (wmx > wmn) ? BWGT : 1.0f;
            const float x = (B.v3 != 0.0f) ? P.w : (1.0f - P.w);
            sum = fmaf(w, -__logf(x), sum);
        }

        // ---- rotate window ----
        A = B; B = C; C = D;
        hasA = true;
        hasC = hasD;
        P = Pn;
    }

    // wave(64) shuffle reduce -> 4-wave LDS reduce -> one partial per block
    #pragma unroll
    for (int off = 32; off > 0; off >>= 1) sum += __shfl_down(sum, off);
    __shared__ float smem[4];
    if ((tid & 63) == 0) smem[tid >> 6] = sum;
    __syncthreads();
    if (tid == 0) partial[blockIdx.x] = (smem[0] + smem[1]) + (smem[2] + smem[3]);
}

__global__ __launch_bounds__(256) void bam_bce_reduce(
    const float* __restrict__ partial, float* __restrict__ out)
{
    const int tid = threadIdx.x;
    float s = 0.0f;
    for (int i = tid; i < GRID1; i += 256) s += partial[i];
    #pragma unroll
    for (int off = 32; off > 0; off >>= 1) s += __shfl_down(s, off);
    __shared__ float smem[4];
    if ((tid & 63) == 0) smem[tid >> 6] = s;
    __syncthreads();
    if (tid == 0) {
        const float invN = 1.0f / (float)((long long)Bn * Hn * Wn);  // 1/2^25, exact
        out[0] = ((smem[0] + smem[1]) + (smem[2] + smem[3])) * invN;
    }
}

extern "C" void kernel_launch(void* const* d_in, const int* in_sizes, int n_in,
                              void* d_out, int out_size, void* d_ws, size_t ws_size,
                              hipStream_t stream)
{
    const float* pred = (const float*)d_in[0];
    const float* tgt  = (const float*)d_in[1];
    float* partial = (float*)d_ws;          // 2048 floats = 8 KB, fully
                                            // overwritten each call (poison-safe)
    bam_bce_rows<<<GRID1, 256, 0, stream>>>(pred, tgt, partial);
    bam_bce_reduce<<<1, 256, 0, stream>>>(partial, (float*)d_out);
}

// Round 3
// 273.800 us; speedup vs baseline: 1.1101x; 1.0504x over previous
//
#include <hip/hip_runtime.h>
#include <math.h>

namespace {
constexpr int Bn = 32, Hn = 1024, Wn = 1024;
constexpr int STRIP = 8;                      // rows per block (divides Hn)
constexpr int GRID1 = Bn * Hn / STRIP;        // 4096 blocks -> 16 KB partials
constexpr float BWGT = 3.0f;
}

__device__ inline float4 vmax4(float4 a, float4 b) {
    return make_float4(fmaxf(a.x,b.x), fmaxf(a.y,b.y), fmaxf(a.z,b.z), fmaxf(a.w,b.w));
}
__device__ inline float4 vmin4(float4 a, float4 b) {
    return make_float4(fminf(a.x,b.x), fminf(a.y,b.y), fminf(a.z,b.z), fminf(a.w,b.w));
}

// Load-all-then-compute: 18 float4 loads issued back-to-back (18 KB/wave in
// flight), one drain, then pure compute. Wave-edge halo columns via one
// batched LDS exchange of raw target edge values. Image borders use the
// binary-target identities (0 for max, 1 for min) == reduce_window's
// -inf/+inf init padding, exact (absmax 0.0 in R2 with same trick).
__global__ __launch_bounds__(256) void bam_bce_rows(
    const float* __restrict__ pred, const float* __restrict__ tgt,
    float* __restrict__ partial)
{
    const int tid  = threadIdx.x;
    const int lane = tid & 63;
    const int wv   = tid >> 6;                // 4 waves per block
    const int x0   = tid << 2;
    const int rowBase = blockIdx.x * STRIP;   // strips never cross images
    const int y0 = rowBase & (Hn - 1);
    const bool vtop = (y0 != 0);              // row y0-1 exists (block-uniform)
    const bool vbot = (y0 != Hn - STRIP);     // row y0+STRIP exists
    const float* tb = tgt  + (size_t)rowBase * Wn;
    const float* pb = pred + (size_t)rowBase * Wn;

    // ---- issue ALL loads up-front: tv[r] = target row y0-1+r, r in 0..9 ----
    float4 tv[STRIP + 2];
    tv[0]         = make_float4(0.f, 0.f, 0.f, 0.f);
    tv[STRIP + 1] = make_float4(0.f, 0.f, 0.f, 0.f);
    if (vtop) tv[0] = *reinterpret_cast<const float4*>(tb - Wn + x0);
    #pragma unroll
    for (int r = 1; r <= STRIP; ++r)
        tv[r] = *reinterpret_cast<const float4*>(tb + (size_t)(r - 1) * Wn + x0);
    if (vbot) tv[STRIP + 1] = *reinterpret_cast<const float4*>(tb + (size_t)STRIP * Wn + x0);
    float4 pv[STRIP];
    #pragma unroll
    for (int r = 0; r < STRIP; ++r)
        pv[r] = *reinterpret_cast<const float4*>(pb + (size_t)r * Wn + x0);

    // ---- batched wave-edge exchange of raw target values (one barrier) ----
    __shared__ float eL[STRIP + 2][4];        // lane 0's column x0   per wave
    __shared__ float eR[STRIP + 2][4];        // lane 63's column x0+3 per wave
    if (lane == 0) {
        #pragma unroll
        for (int r = 0; r < STRIP + 2; ++r) eL[r][wv] = tv[r].x;
    }
    if (lane == 63) {
        #pragma unroll
        for (int r = 0; r < STRIP + 2; ++r) eR[r][wv] = tv[r].w;
    }
    __syncthreads();

    // nbv[r]: raw neighbor-column value for this lane's missing halo side.
    // Only meaningful in lanes 0 (left neighbor) and 63 (right neighbor).
    float nbv[STRIP + 2];
    #pragma unroll
    for (int r = 0; r < STRIP + 2; ++r) nbv[r] = 0.0f;
    if (lane == 0 && wv > 0) {
        #pragma unroll
        for (int r = 0; r < STRIP + 2; ++r) nbv[r] = eR[r][wv - 1];
    }
    if (lane == 63 && wv < 3) {
        #pragma unroll
        for (int r = 0; r < STRIP + 2; ++r) nbv[r] = eL[r][wv + 1];
    }

    float sum = 0.0f;
    #pragma unroll
    for (int i = 0; i < STRIP; ++i) {
        const bool useTop = (i > 0) || vtop;           // row r=i valid
        const bool useBot = (i < STRIP - 1) || vbot;   // row r=i+2 valid

        // vertical (3-row) max/min for own 4 columns + this lane's halo column
        float4 mx = tv[i + 1], mn = tv[i + 1];
        float  em = nbv[i + 1], en = nbv[i + 1];
        if (useTop) {
            mx = vmax4(mx, tv[i]); mn = vmin4(mn, tv[i]);
            em = fmaxf(em, nbv[i]); en = fminf(en, nbv[i]);
        }
        if (useBot) {
            mx = vmax4(mx, tv[i + 2]); mn = vmin4(mn, tv[i + 2]);
            em = fmaxf(em, nbv[i + 2]); en = fminf(en, nbv[i + 2]);
        }

        // horizontal neighbors: in-wave shuffle, patched at wave/image edges
        float Lmx = __shfl_up(mx.w, 1),  Lmn = __shfl_up(mn.w, 1);
        float Rmx = __shfl_down(mx.x, 1), Rmn = __shfl_down(mn.x, 1);
        if (lane == 0)  { Lmx = em; Lmn = en; }
        if (lane == 63) { Rmx = em; Rmn = en; }
        if (tid == 0)   { Lmx = 0.f; Lmn = 1.f; }      // image left border
        if (tid == 255) { Rmx = 0.f; Rmn = 1.f; }      // image right border

        const float4 t = tv[i + 1];
        const float4 p = pv[i];
        {
            const float wmx = fmaxf(fmaxf(Lmx, mx.x), mx.y);
            const float wmn = fminf(fminf(Lmn, mn.x), mn.y);
            const float w = (wmx > wmn) ? BWGT : 1.0f;
            const float x = (t.x != 0.0f) ? p.x : (1.0f - p.x);
            sum = fmaf(w, -__logf(x), sum);
        }
        {
            const float wmx = fmaxf(fmaxf(mx.x, mx.y), mx.z);
            const float wmn = fminf(fminf(mn.x, mn.y), mn.z);
            const float w = (wmx > wmn) ? BWGT : 1.0f;
            const float x = (t.y != 0.0f) ? p.y : (1.0f - p.y);
            sum = fmaf(w, -__logf(x), sum);
        }
        {
            const float wmx = fmaxf(fmaxf(mx.y, mx.z), mx.w);
            const float wmn = fminf(fminf(mn.y, mn.z), mn.w);
            const float w = (wmx > wmn) ? BWGT : 1.0f;
            const float x = (t.z != 0.0f) ? p.z : (1.0f - p.z);
            sum = fmaf(w, -__logf(x), sum);
        }
        {
            const float wmx = fmaxf(fmaxf(mx.z, mx.w), Rmx);
            const float wmn = fminf(fminf(mn.z, mn.w), Rmn);
            const float w = (wmx > wmn) ? BWGT : 1.0f;
            const float x = (t.w != 0.0f) ? p.w : (1.0f - p.w);
            sum = fmaf(w, -__logf(x), sum);
        }
    }

    // wave(64) shuffle reduce -> 4-wave LDS reduce -> one partial per block
    #pragma unroll
    for (int off = 32; off > 0; off >>= 1) sum += __shfl_down(sum, off);
    __shared__ float smem[4];
    if ((tid & 63) == 0) smem[tid >> 6] = sum;
    __syncthreads();
    if (tid == 0) partial[blockIdx.x] = (smem[0] + smem[1]) + (smem[2] + smem[3]);
}

__global__ __launch_bounds__(256) void bam_bce_reduce(
    const float* __restrict__ partial, float* __restrict__ out)
{
    const int tid = threadIdx.x;
    float s = 0.0f;
    for (int i = tid; i < GRID1; i += 256) s += partial[i];
    #pragma unroll
    for (int off = 32; off > 0; off >>= 1) s += __shfl_down(s, off);
    __shared__ float smem[4];
    if ((tid & 63) == 0) smem[tid >> 6] = s;
    __syncthreads();
    if (tid == 0) {
        const float invN = 1.0f / (float)((long long)Bn * Hn * Wn);  // 1/2^25, exact
        out[0] = ((smem[0] + smem[1]) + (smem[2] + smem[3])) * invN;
    }
}

extern "C" void kernel_launch(void* const* d_in, const int* in_sizes, int n_in,
                              void* d_out, int out_size, void* d_ws, size_t ws_size,
                              hipStream_t stream)
{
    const float* pred = (const float*)d_in[0];
    const float* tgt  = (const float*)d_in[1];
    float* partial = (float*)d_ws;            // 4096 floats = 16 KB, fully
                                              // overwritten each call (poison-safe)
    bam_bce_rows<<<GRID1, 256, 0, stream>>>(pred, tgt, partial);
    bam_bce_reduce<<<1, 256, 0, stream>>>(partial, (float*)d_out);
}